// Round 1
// baseline (571.284 us; speedup 1.0000x reference)
//
#include <hip/hip_runtime.h>
#include <hip/hip_bf16.h>

// SpectralDense on MI355X.
// out[8192][2048] = (X[8192][2048] @ K[2048][2048]) / sigma1(K)
// sigma1 via: A~ = K^T K / 4  -> squarings A~^2, A~^4, A~^8 (bf16 GEMMs)
//            -> 20 power-iteration matvecs (4 vectors) -> Rayleigh
//            -> sigma = 2 * R^(1/16).
// Main GEMM: fp16 MFMA 16x16x32, m97 structure (128^2 tile, BK=64,
// global_load_lds w=16, XOR-swizzled LDS, 2-barrier K-loop), epilogue * (1/sigma).
// Workspace use: ~56.1 MB of d_ws.

typedef __attribute__((ext_vector_type(8))) _Float16 f16x8;
typedef __attribute__((ext_vector_type(8))) short   s16x8;
typedef __attribute__((ext_vector_type(4))) float   f32x4;

#define DEV __device__ __forceinline__

DEV unsigned short f2bf(float x) {           // round-to-nearest-even fp32->bf16
  unsigned u = __float_as_uint(x);
  unsigned r = (u + 0x7FFFu + ((u >> 16) & 1u)) >> 16;
  return (unsigned short)r;
}
DEV float bf2f(unsigned short b) { return __uint_as_float(((unsigned)b) << 16); }

DEV void gl_lds16(const void* g, void* l) {
  __builtin_amdgcn_global_load_lds((const __attribute__((address_space(1))) void*)g,
                                   (__attribute__((address_space(3))) void*)l,
                                   16, 0, 0);
}

// ---------------------------------------------------------------------------
// GEMM (B^T layout): C[m][n] = scale * sum_k A[m][k] * B[n][k]
// A: M x K (2-byte elems), B: N x K (2-byte elems), row stride K.
// M,N multiples of 128; K multiple of 64.
// LDS tiles [128][64] elems (128 B rows), XOR swizzle: byte ^= ((row&7)<<4),
// applied on BOTH the global source address (so global_load_lds's linear
// write lands pre-swizzled) and the ds_read side (rule 21: both-or-neither).
// ---------------------------------------------------------------------------
template <bool F16IN, bool F32OUT>
__global__ __launch_bounds__(256, 2)
void gemm_bt(const char* __restrict__ Ag, const char* __restrict__ Bg,
             void* __restrict__ Cg, int M, int N, int K,
             float cscale, const float* __restrict__ scale_ptr)
{
  __shared__ unsigned char smem[32768];     // A: [0,16K), B: [16K,32K)
  const int tid  = threadIdx.x;
  const int lane = tid & 63;
  const int wid  = tid >> 6;

  // XCD-bijective swizzle (all grids here are multiples of 8)
  const int nbm = M >> 7, nbn = N >> 7;
  const int q = (nbm * nbn) >> 3;
  const int wgid = ((int)blockIdx.x & 7) * q + ((int)blockIdx.x >> 3);
  const int bm = wgid % nbm, bn = wgid / nbm;
  const int m0 = bm << 7, n0 = bn << 7;

  float scale = cscale;
  if (scale_ptr) scale *= scale_ptr[0];

  const f32x4 zero = {0.f, 0.f, 0.f, 0.f};
  f32x4 acc[4][4];
#pragma unroll
  for (int i = 0; i < 4; i++)
#pragma unroll
    for (int j = 0; j < 4; j++) acc[i][j] = zero;

  const int wr = wid >> 1, wc = wid & 1;      // 2x2 wave grid, 64x64 per wave
  const size_t rowstride = (size_t)K * 2;     // bytes

  for (int k0 = 0; k0 < K; k0 += 64) {
    // ---- stage A,B tiles: 16 KB each, 4 passes x (256 thr x 16 B) ----
#pragma unroll
    for (int p = 0; p < 4; p++) {
      const int b   = (p << 12) + (wid << 10) + (lane << 4); // linear tile byte
      const int row = b >> 7;                                 // tile row
      const int scb = (b & 127) ^ ((row & 7) << 4);           // swizzled src col byte
      const size_t goff = (size_t)row * rowstride + (size_t)(k0 << 1) + (size_t)scb;
      gl_lds16(Ag + (size_t)m0 * rowstride + goff, smem + (p << 12) + (wid << 10));
      gl_lds16(Bg + (size_t)n0 * rowstride + goff, smem + 16384 + (p << 12) + (wid << 10));
    }
    __syncthreads();   // compiler drains vmcnt before s_barrier

    // ---- compute: 2 K-slices of 32, 16 MFMA each ----
#pragma unroll
    for (int kk = 0; kk < 2; kk++) {
      s16x8 a[4], b[4];
      const int kb = (kk << 6) + ((lane >> 4) << 4);  // byte offset in 128B row
#pragma unroll
      for (int i = 0; i < 4; i++) {
        const int ar = (wr << 6) + (i << 4) + (lane & 15);
        const int br = (wc << 6) + (i << 4) + (lane & 15);
        a[i] = *(const s16x8*)(smem + ((((ar << 7) + kb)) ^ ((ar & 7) << 4)));
        b[i] = *(const s16x8*)(smem + 16384 + ((((br << 7) + kb)) ^ ((br & 7) << 4)));
      }
#pragma unroll
      for (int i = 0; i < 4; i++)
#pragma unroll
        for (int j = 0; j < 4; j++) {
          if constexpr (F16IN)
            acc[i][j] = __builtin_amdgcn_mfma_f32_16x16x32_f16(
                __builtin_bit_cast(f16x8, a[i]), __builtin_bit_cast(f16x8, b[j]),
                acc[i][j], 0, 0, 0);
          else
            acc[i][j] = __builtin_amdgcn_mfma_f32_16x16x32_bf16(
                a[i], b[j], acc[i][j], 0, 0, 0);
        }
    }
    __syncthreads();
  }

  // ---- epilogue: C/D layout col = lane&15, row = (lane>>4)*4 + reg (m89) ----
  const int ccol = n0 + (wc << 6) + (lane & 15);
  const int crow = m0 + (wr << 6) + ((lane >> 4) << 2);
#pragma unroll
  for (int i = 0; i < 4; i++)
#pragma unroll
    for (int j = 0; j < 4; j++)
#pragma unroll
      for (int r = 0; r < 4; r++) {
        const int rr = crow + (i << 4) + r;
        const int cc = ccol + (j << 4);
        const float v = acc[i][j][r] * scale;
        if constexpr (F32OUT)
          ((float*)Cg)[(size_t)rr * (size_t)N + cc] = v;
        else
          ((unsigned short*)Cg)[(size_t)rr * (size_t)N + cc] = f2bf(v);
      }
}

// ---------------------------------------------------------------------------
// y[row][0..3] = sum_c C_bf16[row][c] * v[c][0..3]   (2048 rows, 4 vectors)
// one wave per row; lane covers 32 contiguous cols (64 B coalesced)
// ---------------------------------------------------------------------------
__global__ __launch_bounds__(256)
void matvec4(const unsigned short* __restrict__ Cm,
             const float* __restrict__ vin, float* __restrict__ vout)
{
  const int row  = ((int)blockIdx.x << 2) + ((int)threadIdx.x >> 6);
  const int lane = threadIdx.x & 63;
  const unsigned short* crow = Cm + ((size_t)row << 11) + (lane << 5);
  const float* vp = vin + (lane << 7);
  float s0 = 0.f, s1 = 0.f, s2 = 0.f, s3 = 0.f;
#pragma unroll
  for (int u = 0; u < 4; u++) {
    const s16x8 cv = *(const s16x8*)(crow + (u << 3));
#pragma unroll
    for (int e = 0; e < 8; e++) {
      const float w = bf2f((unsigned short)cv[e]);
      const f32x4 vv = *(const f32x4*)(vp + (((u << 3) + e) << 2));
      s0 += w * vv[0]; s1 += w * vv[1]; s2 += w * vv[2]; s3 += w * vv[3];
    }
  }
#pragma unroll
  for (int d = 32; d > 0; d >>= 1) {
    s0 += __shfl_down(s0, d);
    s1 += __shfl_down(s1, d);
    s2 += __shfl_down(s2, d);
    s3 += __shfl_down(s3, d);
  }
  if (lane == 0) {
    float* o = vout + ((size_t)row << 2);
    o[0] = s0; o[1] = s1; o[2] = s2; o[3] = s3;
  }
}

__global__ void init_v(float* __restrict__ v) {
  const int i = (int)blockIdx.x * 256 + (int)threadIdx.x;  // 8192 values
  unsigned h = (unsigned)i * 2654435761u;
  h ^= h >> 16; h *= 2246822519u; h ^= h >> 13;
  v[i] = (float)(h & 0xFFFFFFu) * (2.0f / 16777216.0f) - 1.0f;
}

// R_j = (vt_j . y_j) / (vt_j . vt_j); sigma = 2 * max_j R_j ^ (1/16); sig[0]=1/sigma
__global__ __launch_bounds__(256)
void rayleigh_k(const float* __restrict__ vt, const float* __restrict__ y,
                float* __restrict__ sig)
{
  __shared__ float part[4][8];
  const int t = threadIdx.x, lane = t & 63, w = t >> 6;
  float num[4] = {0, 0, 0, 0}, den[4] = {0, 0, 0, 0};
  for (int i = t; i < 2048; i += 256) {
    const f32x4 a = *(const f32x4*)(vt + ((size_t)i << 2));
    const f32x4 b = *(const f32x4*)(y + ((size_t)i << 2));
#pragma unroll
    for (int j = 0; j < 4; j++) { num[j] += a[j] * b[j]; den[j] += a[j] * a[j]; }
  }
#pragma unroll
  for (int d = 32; d > 0; d >>= 1)
#pragma unroll
    for (int j = 0; j < 4; j++) {
      num[j] += __shfl_down(num[j], d);
      den[j] += __shfl_down(den[j], d);
    }
  if (lane == 0) {
#pragma unroll
    for (int j = 0; j < 4; j++) { part[w][j] = num[j]; part[w][j + 4] = den[j]; }
  }
  __syncthreads();
  if (t == 0) {
    float R = 0.f;
#pragma unroll
    for (int j = 0; j < 4; j++) {
      const float nj = part[0][j] + part[1][j] + part[2][j] + part[3][j];
      const float dj = part[0][j + 4] + part[1][j + 4] + part[2][j + 4] + part[3][j + 4];
      R = fmaxf(R, nj / dj);
    }
    const float sigma = 2.0f * powf(R, 0.0625f);
    sig[0] = 1.0f / sigma;
  }
}

__global__ __launch_bounds__(256)
void convert_f16(const float* __restrict__ in, _Float16* __restrict__ out) {
  const size_t i = (((size_t)blockIdx.x * 256) + threadIdx.x) << 3;
  const f32x4 a = *(const f32x4*)(in + i);
  const f32x4 b = *(const f32x4*)(in + i + 4);
  f16x8 o;
#pragma unroll
  for (int e = 0; e < 4; e++) { o[e] = (_Float16)a[e]; o[e + 4] = (_Float16)b[e]; }
  *(f16x8*)(out + i) = o;
}

// KT[f][d] = (f16) K[d][f], 64x64 tiles via LDS (stride 65: conflict-free)
__global__ __launch_bounds__(256)
void transpose_f16(const float* __restrict__ Kin, _Float16* __restrict__ KT) {
  __shared__ float tile[64][65];
  const int t = threadIdx.x;
  const int c = t & 63, rq = t >> 6;
  const int d0 = (int)blockIdx.x << 6, f0 = (int)blockIdx.y << 6;
#pragma unroll
  for (int p = 0; p < 16; p++) {
    const int rr = (p << 2) + rq;
    tile[rr][c] = Kin[(size_t)(d0 + rr) * 2048 + f0 + c];
  }
  __syncthreads();
#pragma unroll
  for (int p = 0; p < 16; p++) {
    const int fl = (p << 2) + rq;
    KT[(size_t)(f0 + fl) * 2048 + d0 + c] = (_Float16)tile[c][fl];
  }
}

// ---------------------------------------------------------------------------
extern "C" void kernel_launch(void* const* d_in, const int* in_sizes, int n_in,
                              void* d_out, int out_size, void* d_ws, size_t ws_size,
                              hipStream_t stream)
{
  (void)in_sizes; (void)n_in; (void)out_size; (void)ws_size;
  const float* X  = (const float*)d_in[0];   // [8192][2048] fp32
  const float* Km = (const float*)d_in[1];   // [2048][2048] fp32
  float* out = (float*)d_out;                // [8192][2048] fp32
  char* ws = (char*)d_ws;

  _Float16* X16 = (_Float16*)ws;                      // 32 MiB
  _Float16* KT  = (_Float16*)(ws + (32u << 20));      // 8 MiB  (K^T, f16)
  char* buf0 = ws + (40u << 20);                      // 8 MiB  bf16 2048^2
  char* buf1 = ws + (48u << 20);                      // 8 MiB  bf16 2048^2
  float* V0  = (float*)(ws + (56u << 20));            // 2048 x 4
  float* V1  = V0 + 8192;
  float* sig = V1 + 8192;

  convert_f16<<<8192, 256, 0, stream>>>(X, X16);
  transpose_f16<<<dim3(32, 32), 256, 0, stream>>>(Km, KT);

  // A~ = (K^T K)/4 : A[i][j] = 0.25 * sum_d KT[i][d]*KT[j][d]  (f16 in, bf16 out)
  gemm_bt<true, false><<<256, 256, 0, stream>>>((const char*)KT, (const char*)KT,
                                                buf0, 2048, 2048, 2048, 0.25f, nullptr);
  // squarings (symmetric: P*P == P*P^T), bf16 chain: A~^2, A~^4, A~^8
  gemm_bt<false, false><<<256, 256, 0, stream>>>(buf0, buf0, buf1, 2048, 2048, 2048, 1.0f, nullptr);
  gemm_bt<false, false><<<256, 256, 0, stream>>>(buf1, buf1, buf0, 2048, 2048, 2048, 1.0f, nullptr);
  gemm_bt<false, false><<<256, 256, 0, stream>>>(buf0, buf0, buf1, 2048, 2048, 2048, 1.0f, nullptr);

  // power iteration on C = A~^8 (in buf1), 4 vectors, 20 multiplies
  init_v<<<32, 256, 0, stream>>>(V0);
  for (int it = 0; it < 20; it++)
    matvec4<<<512, 256, 0, stream>>>((const unsigned short*)buf1,
                                     (it & 1) ? V1 : V0, (it & 1) ? V0 : V1);
  // vt = V1 (input of last multiply), y = V0 (its output)
  rayleigh_k<<<1, 256, 0, stream>>>(V1, V0, sig);

  // out = X @ K / sigma : out[m][f] = sig * sum_d X16[m][d]*KT[f][d]
  gemm_bt<true, true><<<1024, 256, 0, stream>>>((const char*)X16, (const char*)KT,
                                                out, 8192, 2048, 2048, 1.0f, sig);
}

// Round 2
// 492.303 us; speedup vs baseline: 1.1604x; 1.1604x over previous
//
#include <hip/hip_runtime.h>
#include <hip/hip_bf16.h>

// SpectralDense on MI355X.
// out[8192][2048] = (X[8192][2048] @ K[2048][2048]) / sigma1(K)
// sigma1 via: A~ = K^T K / 4 -> 4 squarings (bf16 GEMMs, split-K=2) -> C=A~^16
//            -> 10 power-iteration matvecs (4 vectors) -> Rayleigh
//            -> sigma = 2 * R^(1/32).
// Main GEMM: fp16 MFMA 16x16x32, m97 structure (128^2 tile, BK=64,
// global_load_lds w=16, XOR-swizzled LDS, 2-barrier K-loop), epilogue * (1/sigma).
// Chain GEMMs: same kernel, grid (256,2) split-K (2 blocks/CU) -> fp32 partials
// -> reduce+cast to bf16.
// Workspace use: ~88.3 MB of d_ws.

typedef __attribute__((ext_vector_type(8))) _Float16 f16x8;
typedef __attribute__((ext_vector_type(8))) short   s16x8;
typedef __attribute__((ext_vector_type(4))) float   f32x4;

#define DEV __device__ __forceinline__

DEV unsigned short f2bf(float x) {           // round-to-nearest-even fp32->bf16
  unsigned u = __float_as_uint(x);
  unsigned r = (u + 0x7FFFu + ((u >> 16) & 1u)) >> 16;
  return (unsigned short)r;
}
DEV float bf2f(unsigned short b) { return __uint_as_float(((unsigned)b) << 16); }

DEV void gl_lds16(const void* g, void* l) {
  __builtin_amdgcn_global_load_lds((const __attribute__((address_space(1))) void*)g,
                                   (__attribute__((address_space(3))) void*)l,
                                   16, 0, 0);
}

// ---------------------------------------------------------------------------
// GEMM (B^T layout): C[m][n] = scale * sum_{k in my split} A[m][k] * B[n][k]
// A: M x K (2-byte elems), B: N x K (2-byte elems), row stride K.
// M,N multiples of 128; K multiple of (64 * gridDim.y).
// Split-K across gridDim.y: block (x,y) computes K-range y*(K/gy) .. and
// writes fp32 to Cg + y*M*N (partials summed by reduce_bf16).
// LDS tiles [128][64] elems (128 B rows), XOR swizzle: byte ^= ((row&7)<<4),
// applied on BOTH the global source address (so global_load_lds's linear
// write lands pre-swizzled) and the ds_read side (rule 21: both-or-neither).
// ---------------------------------------------------------------------------
template <bool F16IN>
__global__ __launch_bounds__(256, 2)
void gemm_bt(const char* __restrict__ Ag, const char* __restrict__ Bg,
             float* __restrict__ Cg, int M, int N, int K,
             float cscale, const float* __restrict__ scale_ptr)
{
  __shared__ unsigned char smem[32768];     // A: [0,16K), B: [16K,32K)
  const int tid  = threadIdx.x;
  const int lane = tid & 63;
  const int wid  = tid >> 6;

  // XCD-bijective swizzle over blockIdx.x (all grid.x here are multiples of 8)
  const int nbm = M >> 7, nbn = N >> 7;
  const int q = (nbm * nbn) >> 3;
  const int wgid = ((int)blockIdx.x & 7) * q + ((int)blockIdx.x >> 3);
  const int bm = wgid % nbm, bn = wgid / nbm;
  const int m0 = bm << 7, n0 = bn << 7;

  // split-K range and partial-output base
  const int ksz  = K / (int)gridDim.y;
  const int kbeg = (int)blockIdx.y * ksz;
  float* __restrict__ Cmy = Cg + (size_t)blockIdx.y * (size_t)M * (size_t)N;

  float scale = cscale;
  if (scale_ptr) scale *= scale_ptr[0];

  const f32x4 zero = {0.f, 0.f, 0.f, 0.f};
  f32x4 acc[4][4];
#pragma unroll
  for (int i = 0; i < 4; i++)
#pragma unroll
    for (int j = 0; j < 4; j++) acc[i][j] = zero;

  const int wr = wid >> 1, wc = wid & 1;      // 2x2 wave grid, 64x64 per wave
  const size_t rowstride = (size_t)K * 2;     // bytes

  for (int k0 = kbeg; k0 < kbeg + ksz; k0 += 64) {
    // ---- stage A,B tiles: 16 KB each, 4 passes x (256 thr x 16 B) ----
#pragma unroll
    for (int p = 0; p < 4; p++) {
      const int b   = (p << 12) + (wid << 10) + (lane << 4); // linear tile byte
      const int row = b >> 7;                                 // tile row
      const int scb = (b & 127) ^ ((row & 7) << 4);           // swizzled src col byte
      const size_t goff = (size_t)row * rowstride + (size_t)(k0 << 1) + (size_t)scb;
      gl_lds16(Ag + (size_t)m0 * rowstride + goff, smem + (p << 12) + (wid << 10));
      gl_lds16(Bg + (size_t)n0 * rowstride + goff, smem + 16384 + (p << 12) + (wid << 10));
    }
    __syncthreads();   // compiler drains vmcnt before s_barrier

    // ---- compute: 2 K-slices of 32, 16 MFMA each ----
#pragma unroll
    for (int kk = 0; kk < 2; kk++) {
      s16x8 a[4], b[4];
      const int kb = (kk << 6) + ((lane >> 4) << 4);  // byte offset in 128B row
#pragma unroll
      for (int i = 0; i < 4; i++) {
        const int ar = (wr << 6) + (i << 4) + (lane & 15);
        const int br = (wc << 6) + (i << 4) + (lane & 15);
        a[i] = *(const s16x8*)(smem + ((((ar << 7) + kb)) ^ ((ar & 7) << 4)));
        b[i] = *(const s16x8*)(smem + 16384 + ((((br << 7) + kb)) ^ ((br & 7) << 4)));
      }
#pragma unroll
      for (int i = 0; i < 4; i++)
#pragma unroll
        for (int j = 0; j < 4; j++) {
          if constexpr (F16IN)
            acc[i][j] = __builtin_amdgcn_mfma_f32_16x16x32_f16(
                __builtin_bit_cast(f16x8, a[i]), __builtin_bit_cast(f16x8, b[j]),
                acc[i][j], 0, 0, 0);
          else
            acc[i][j] = __builtin_amdgcn_mfma_f32_16x16x32_bf16(
                a[i], b[j], acc[i][j], 0, 0, 0);
        }
    }
    __syncthreads();
  }

  // ---- epilogue: C/D layout col = lane&15, row = (lane>>4)*4 + reg (m89) ----
  const int ccol = n0 + (wc << 6) + (lane & 15);
  const int crow = m0 + (wr << 6) + ((lane >> 4) << 2);
#pragma unroll
  for (int i = 0; i < 4; i++)
#pragma unroll
    for (int j = 0; j < 4; j++)
#pragma unroll
      for (int r = 0; r < 4; r++) {
        const int rr = crow + (i << 4) + r;
        const int cc = ccol + (j << 4);
        Cmy[(size_t)rr * (size_t)N + cc] = acc[i][j][r] * scale;
      }
}

// o_bf16[i] = (bf16)(a[i] + b[i])  — split-K partial reduce, 8 elems/thread
__global__ __launch_bounds__(256)
void reduce_bf16(const float* __restrict__ a, const float* __restrict__ b,
                 unsigned short* __restrict__ o)
{
  const size_t i = (((size_t)blockIdx.x * 256) + threadIdx.x) << 3;
  const f32x4 a0 = *(const f32x4*)(a + i);
  const f32x4 a1 = *(const f32x4*)(a + i + 4);
  const f32x4 b0 = *(const f32x4*)(b + i);
  const f32x4 b1 = *(const f32x4*)(b + i + 4);
  s16x8 r;
#pragma unroll
  for (int e = 0; e < 4; e++) {
    r[e]     = (short)f2bf(a0[e] + b0[e]);
    r[e + 4] = (short)f2bf(a1[e] + b1[e]);
  }
  *(s16x8*)(o + i) = r;
}

// ---------------------------------------------------------------------------
// y[row][0..3] = sum_c C_bf16[row][c] * v[c][0..3]   (2048 rows, 4 vectors)
// one wave per row; lane covers 32 contiguous cols (64 B coalesced)
// ---------------------------------------------------------------------------
__global__ __launch_bounds__(256)
void matvec4(const unsigned short* __restrict__ Cm,
             const float* __restrict__ vin, float* __restrict__ vout)
{
  const int row  = ((int)blockIdx.x << 2) + ((int)threadIdx.x >> 6);
  const int lane = threadIdx.x & 63;
  const unsigned short* crow = Cm + ((size_t)row << 11) + (lane << 5);
  const float* vp = vin + (lane << 7);
  float s0 = 0.f, s1 = 0.f, s2 = 0.f, s3 = 0.f;
#pragma unroll
  for (int u = 0; u < 4; u++) {
    const s16x8 cv = *(const s16x8*)(crow + (u << 3));
#pragma unroll
    for (int e = 0; e < 8; e++) {
      const float w = bf2f((unsigned short)cv[e]);
      const f32x4 vv = *(const f32x4*)(vp + (((u << 3) + e) << 2));
      s0 += w * vv[0]; s1 += w * vv[1]; s2 += w * vv[2]; s3 += w * vv[3];
    }
  }
#pragma unroll
  for (int d = 32; d > 0; d >>= 1) {
    s0 += __shfl_down(s0, d);
    s1 += __shfl_down(s1, d);
    s2 += __shfl_down(s2, d);
    s3 += __shfl_down(s3, d);
  }
  if (lane == 0) {
    float* o = vout + ((size_t)row << 2);
    o[0] = s0; o[1] = s1; o[2] = s2; o[3] = s3;
  }
}

__global__ void init_v(float* __restrict__ v) {
  const int i = (int)blockIdx.x * 256 + (int)threadIdx.x;  // 8192 values
  unsigned h = (unsigned)i * 2654435761u;
  h ^= h >> 16; h *= 2246822519u; h ^= h >> 13;
  v[i] = (float)(h & 0xFFFFFFu) * (2.0f / 16777216.0f) - 1.0f;
}

// R_j = (vt_j . y_j) / (vt_j . vt_j); sigma = 2 * max_j R_j ^ (1/32); sig[0]=1/sigma
__global__ __launch_bounds__(256)
void rayleigh_k(const float* __restrict__ vt, const float* __restrict__ y,
                float* __restrict__ sig)
{
  __shared__ float part[4][8];
  const int t = threadIdx.x, lane = t & 63, w = t >> 6;
  float num[4] = {0, 0, 0, 0}, den[4] = {0, 0, 0, 0};
  for (int i = t; i < 2048; i += 256) {
    const f32x4 a = *(const f32x4*)(vt + ((size_t)i << 2));
    const f32x4 b = *(const f32x4*)(y + ((size_t)i << 2));
#pragma unroll
    for (int j = 0; j < 4; j++) { num[j] += a[j] * b[j]; den[j] += a[j] * a[j]; }
  }
#pragma unroll
  for (int d = 32; d > 0; d >>= 1)
#pragma unroll
    for (int j = 0; j < 4; j++) {
      num[j] += __shfl_down(num[j], d);
      den[j] += __shfl_down(den[j], d);
    }
  if (lane == 0) {
#pragma unroll
    for (int j = 0; j < 4; j++) { part[w][j] = num[j]; part[w][j + 4] = den[j]; }
  }
  __syncthreads();
  if (t == 0) {
    float R = 0.f;
#pragma unroll
    for (int j = 0; j < 4; j++) {
      const float nj = part[0][j] + part[1][j] + part[2][j] + part[3][j];
      const float dj = part[0][j + 4] + part[1][j + 4] + part[2][j + 4] + part[3][j + 4];
      R = fmaxf(R, nj / dj);
    }
    const float sigma = 2.0f * powf(R, 0.03125f);   // R^(1/32)
    sig[0] = 1.0f / sigma;
  }
}

__global__ __launch_bounds__(256)
void convert_f16(const float* __restrict__ in, _Float16* __restrict__ out) {
  const size_t i = (((size_t)blockIdx.x * 256) + threadIdx.x) << 3;
  const f32x4 a = *(const f32x4*)(in + i);
  const f32x4 b = *(const f32x4*)(in + i + 4);
  f16x8 o;
#pragma unroll
  for (int e = 0; e < 4; e++) { o[e] = (_Float16)a[e]; o[e + 4] = (_Float16)b[e]; }
  *(f16x8*)(out + i) = o;
}

// KT[f][d] = (f16) K[d][f], 64x64 tiles via LDS (stride 65: conflict-free)
__global__ __launch_bounds__(256)
void transpose_f16(const float* __restrict__ Kin, _Float16* __restrict__ KT) {
  __shared__ float tile[64][65];
  const int t = threadIdx.x;
  const int c = t & 63, rq = t >> 6;
  const int d0 = (int)blockIdx.x << 6, f0 = (int)blockIdx.y << 6;
#pragma unroll
  for (int p = 0; p < 16; p++) {
    const int rr = (p << 2) + rq;
    tile[rr][c] = Kin[(size_t)(d0 + rr) * 2048 + f0 + c];
  }
  __syncthreads();
#pragma unroll
  for (int p = 0; p < 16; p++) {
    const int fl = (p << 2) + rq;
    KT[(size_t)(f0 + fl) * 2048 + d0 + c] = (_Float16)tile[c][fl];
  }
}

// ---------------------------------------------------------------------------
extern "C" void kernel_launch(void* const* d_in, const int* in_sizes, int n_in,
                              void* d_out, int out_size, void* d_ws, size_t ws_size,
                              hipStream_t stream)
{
  (void)in_sizes; (void)n_in; (void)out_size; (void)ws_size;
  const float* X  = (const float*)d_in[0];   // [8192][2048] fp32
  const float* Km = (const float*)d_in[1];   // [2048][2048] fp32
  float* out = (float*)d_out;                // [8192][2048] fp32
  char* ws = (char*)d_ws;

  _Float16* X16 = (_Float16*)ws;                      // 32 MiB
  _Float16* KT  = (_Float16*)(ws + (32u << 20));      // 8 MiB  (K^T, f16)
  unsigned short* buf0 = (unsigned short*)(ws + (40u << 20)); // 8 MiB bf16 2048^2
  unsigned short* buf1 = (unsigned short*)(ws + (48u << 20)); // 8 MiB bf16 2048^2
  float* P   = (float*)(ws + (56u << 20));            // 32 MiB: 2 fp32 partials
  float* V0  = (float*)(ws + (88u << 20));            // 2048 x 4
  float* V1  = V0 + 8192;
  float* sig = V1 + 8192;

  const size_t PN = (size_t)2048 * 2048;              // partial plane elems

  convert_f16<<<8192, 256, 0, stream>>>(X, X16);
  transpose_f16<<<dim3(32, 32), 256, 0, stream>>>(Km, KT);

  // A~ = (K^T K)/4, split-K=2 -> fp32 partials -> bf16
  gemm_bt<true><<<dim3(256, 2), 256, 0, stream>>>((const char*)KT, (const char*)KT,
                                                  P, 2048, 2048, 2048, 0.25f, nullptr);
  reduce_bf16<<<2048, 256, 0, stream>>>(P, P + PN, buf0);

  // 4 squarings (symmetric: S*S == S*S^T): A~^2, A~^4, A~^8, A~^16
  unsigned short* src = buf0;
  unsigned short* dst = buf1;
  for (int s = 0; s < 4; s++) {
    gemm_bt<false><<<dim3(256, 2), 256, 0, stream>>>((const char*)src, (const char*)src,
                                                     P, 2048, 2048, 2048, 1.0f, nullptr);
    reduce_bf16<<<2048, 256, 0, stream>>>(P, P + PN, dst);
    unsigned short* t = src; src = dst; dst = t;
  }
  // C = A~^16 now in `src` (buf0)

  // power iteration on C, 4 vectors, 10 multiplies
  init_v<<<32, 256, 0, stream>>>(V0);
  for (int it = 0; it < 10; it++)
    matvec4<<<512, 256, 0, stream>>>(src, (it & 1) ? V1 : V0, (it & 1) ? V0 : V1);
  // vt = V1 (input of last multiply), y = V0 (its output)
  rayleigh_k<<<1, 256, 0, stream>>>(V1, V0, sig);

  // out = X @ K / sigma : out[m][f] = sig * sum_d X16[m][d]*KT[f][d]
  gemm_bt<true><<<dim3(1024, 1), 256, 0, stream>>>((const char*)X16, (const char*)KT,
                                                   out, 8192, 2048, 2048, 1.0f, sig);
}